// Round 23
// baseline (145.109 us; speedup 1.0000x reference)
//
#include <hip/hip_runtime.h>
#include <hip/hip_bf16.h>

#define TT 1024
#define DD 64
#define MAXREL 16
#define NV 33
#define QBLK 16
#define SCALE 0.125f
#define BH 64
#define NW 10

typedef short bf16x8 __attribute__((ext_vector_type(8)));
typedef short bf16x4 __attribute__((ext_vector_type(4)));
typedef float f32x4 __attribute__((ext_vector_type(4)));

#define SBAR() __builtin_amdgcn_sched_barrier(0)
#define WAITV(N)   __builtin_amdgcn_s_waitcnt(0x0F70 | (N))   // lgkm=15, exp=7, vm=N
#define WAITLGKM() __builtin_amdgcn_s_waitcnt(0xC07F)          // vm=63, exp=7, lgkm=0

static __device__ inline void gload16(const void* g, void* l) {
    __builtin_amdgcn_global_load_lds(
        (const __attribute__((address_space(1))) void*)g,
        (__attribute__((address_space(3))) void*)l, 16, 0, 0);
}

static __device__ inline short f2bf(float f) {
    __hip_bfloat16 h = __float2bfloat16(f);
    return *(short*)&h;
}
static __device__ inline float bf2f(short s) {
    union { unsigned u; float f; } x;
    x.u = ((unsigned)(unsigned short)s) << 16;
    return x.f;
}
static __device__ inline bf16x8 pack8(float4 a, float4 b) {
    bf16x8 r;
    r[0]=f2bf(a.x); r[1]=f2bf(a.y); r[2]=f2bf(a.z); r[3]=f2bf(a.w);
    r[4]=f2bf(b.x); r[5]=f2bf(b.y); r[6]=f2bf(b.z); r[7]=f2bf(b.w);
    return r;
}

// ---- fused pre-kernel: K f32->bf16 copy + V f32->bf16 transpose ----
__global__ __launch_bounds__(256)
void prep_kernel(const float* __restrict__ k, const float* __restrict__ v,
                 short* __restrict__ kbuf, short* __restrict__ vt) {
    __shared__ short tile[64][66];
    const int bh = blockIdx.x >> 4;
    const int s0 = (blockIdx.x & 15) * 64;
    const int t  = threadIdx.x;
    const int r  = t >> 2;
    const int g  = t & 3;
    {
        const float* kp = k + ((size_t)bh * TT + s0 + r) * DD + g * 16;
        float4 a0 = *(const float4*)(kp);
        float4 a1 = *(const float4*)(kp + 4);
        float4 a2 = *(const float4*)(kp + 8);
        float4 a3 = *(const float4*)(kp + 12);
        short* dp = kbuf + ((size_t)bh * TT + s0 + r) * DD + g * 16;
        *(bf16x8*)dp       = pack8(a0, a1);
        *(bf16x8*)(dp + 8) = pack8(a2, a3);
    }
    {
        const float* vp = v + ((size_t)bh * TT + s0 + r) * DD + g * 16;
        float4 a0 = *(const float4*)(vp);
        float4 a1 = *(const float4*)(vp + 4);
        float4 a2 = *(const float4*)(vp + 8);
        float4 a3 = *(const float4*)(vp + 12);
        bf16x8 b0 = pack8(a0, a1), b1 = pack8(a2, a3);
        #pragma unroll
        for (int j = 0; j < 8; ++j) {
            tile[g * 16 + j][r]     = b0[j];
            tile[g * 16 + 8 + j][r] = b1[j];
        }
    }
    __syncthreads();
    {
        const int d = t >> 2, c = t & 3;
        bf16x8 o0 = *(const bf16x8*)&tile[d][c * 16];
        bf16x8 o1 = *(const bf16x8*)&tile[d][c * 16 + 8];
        short* dp = vt + ((size_t)bh * DD + d) * TT + s0 + c * 16;
        *(bf16x8*)dp       = o0;
        *(bf16x8*)(dp + 8) = o1;
    }
}

__global__ __launch_bounds__(640)
void relattn_kernel(const float* __restrict__ q_g,
                    const short* __restrict__ kb,
                    const short* __restrict__ vt,
                    const float* __restrict__ ek_g,
                    const float* __restrict__ ev_g,
                    float* __restrict__ out_g,
                    float* __restrict__ attn_g) {
    __shared__ __align__(16) char pbuf[QBLK * 2048];     // 32768 B bf16 P, swizzled
    __shared__ __align__(16) char kstage[NW * 4096];     // 40960 B per-wave K/V dbuf
    __shared__ short pair_lds[4][16][16];                // 2048 B (bf16)
    __shared__ float qe_lds[QBLK * NV];                  // 2112 B
    __shared__ float w_lds[QBLK * NV];                   // 2112 B
    __shared__ short psum_lds[QBLK][NW];                 // 320 B (bf16)
    __shared__ short psuf_lds[QBLK][NW];
    __shared__ short pmid_lds[QBLK][NW];
    __shared__ float inv_lds[QBLK];                      // 64 B

    const int t    = threadIdx.x;
    const int bid  = blockIdx.x;
    const int wg   = ((bid & 7) << 9) | (bid >> 3);      // XCD swizzle
    const int bh   = wg >> 6;
    const int q0   = (wg & 63) * QBLK;
    const int w    = t >> 6;                             // wave 0..9
    const int lane = t & 63;
    const int lr   = lane & 15;
    const int akg  = lane >> 4;
    const int srl  = lane >> 3;
    const int sqg  = (lane & 7) ^ srl;

    // uneven C split: waves 0..3 own 7 K-tiles, waves 4..9 own 6 (4*7+6*6=64)
    const int start = (w < 4) ? (7 * w) : (28 + 6 * (w - 4));
    const bool real7 = (w < 4);

    const short* kgbase = kb + (size_t)bh * TT * DD;
    char* kst = kstage + w * 4096;

    auto KSTAGE = [&](int B, int TILE) {
        const int tc = TILE > 63 ? 63 : TILE;            // clamp (dummy-slot safety)
        const int s0 = tc * 16;
        gload16(kgbase + (size_t)(s0 + srl) * 64 + sqg * 8,     kst + B * 2048);
        gload16(kgbase + (size_t)(s0 + 8 + srl) * 64 + sqg * 8, kst + B * 2048 + 1024);
    };

    // Q fragment (B operand of swapped MFMA): Q[q0+lr][...]
    bf16x8 qF0, qF1;
    {
        const float* qp = q_g + ((size_t)bh * TT + q0 + lr) * DD + akg * 8;
        float4 a = *(const float4*)qp,        b = *(const float4*)(qp + 4);
        float4 c = *(const float4*)(qp + 32), d = *(const float4*)(qp + 36);
        qF0 = pack8(a, b); qF1 = pack8(c, d);
    }

    // Prologue hoist: stage first two K tiles
    KSTAGE(0, start); KSTAGE(1, start + 1);

    // ---- Phase A: zero w; eqe = exp(qe/8) via MFMA (waves 0..2) ----
    for (int i = t; i < QBLK * NV; i += 640) w_lds[i] = 0.f;
    if (w < 3) {
        int v = w * 16 + lr; if (v > 32) v = 32;
        const float* ep = ek_g + v * DD + akg * 8;
        float4 a = *(const float4*)ep,        b = *(const float4*)(ep + 4);
        float4 c = *(const float4*)(ep + 32), d = *(const float4*)(ep + 36);
        bf16x8 eF0 = pack8(a, b), eF1 = pack8(c, d);
        f32x4 qacc = {0.f, 0.f, 0.f, 0.f};
        qacc = __builtin_amdgcn_mfma_f32_16x16x32_bf16(eF0, qF0, qacc, 0, 0, 0);
        qacc = __builtin_amdgcn_mfma_f32_16x16x32_bf16(eF1, qF1, qacc, 0, 0, 0);
        #pragma unroll
        for (int j = 0; j < 4; ++j) {
            int vv = w * 16 + akg * 4 + j;
            if (vv < NV) qe_lds[lr * NV + vv] = __expf(qacc[j] * SCALE);
        }
    }
    __syncthreads();

    // ---- Phase C: per-wave 6-or-7 K-tiles, dbuf staged ----
    {
        const int tq = q0 + lr;
        const int X  = (lr & 7) << 4;
        const float eqe_lo = qe_lds[lr * NV];
        const float eqe_hi = qe_lds[lr * NV + 32];
        float sum = 0.f, suff = 0.f, msum = 0.f;

        auto CVALU = [&](f32x4 acc, int TILE) {
            const int sb = TILE * 16 + akg * 4;
            float ex0 = __expf(acc[0] * SCALE), ex1 = __expf(acc[1] * SCALE);
            float ex2 = __expf(acc[2] * SCALE), ex3 = __expf(acc[3] * SCALE);
            float e0, e1, e2, e3;
            if (sb >= tq + MAXREL) {               // fully suffix
                e0 = ex0 * eqe_hi; e1 = ex1 * eqe_hi;
                e2 = ex2 * eqe_hi; e3 = ex3 * eqe_hi;
                float csum = (e0 + e1) + (e2 + e3);
                sum += csum; suff += csum;
            } else if (sb + 3 <= tq - MAXREL) {    // fully prefix
                e0 = ex0 * eqe_lo; e1 = ex1 * eqe_lo;
                e2 = ex2 * eqe_lo; e3 = ex3 * eqe_lo;
                sum += (e0 + e1) + (e2 + e3);
            } else {                               // diagonal band (rare)
                float ee[4]; float exs[4] = {ex0, ex1, ex2, ex3};
                #pragma unroll
                for (int j = 0; j < 4; ++j) {
                    int dr = sb + j - tq;
                    int dc = dr < -MAXREL ? -MAXREL : (dr > MAXREL ? MAXREL : dr);
                    float v = exs[j] * qe_lds[lr * NV + dc + MAXREL];
                    ee[j] = v;
                    sum += v;
                    if (dr >= MAXREL) suff += v;
                    if (dr > -MAXREL && dr < MAXREL) {
                        w_lds[lr * NV + dr + MAXREL] = v;
                        msum += v;
                    }
                }
                e0 = ee[0]; e1 = ee[1]; e2 = ee[2]; e3 = ee[3];
            }
            bf16x4 p4;
            p4[0] = f2bf(e0); p4[1] = f2bf(e1);
            p4[2] = f2bf(e2); p4[3] = f2bf(e3);
            *(bf16x4*)(pbuf + lr * 2048 + ((2 * sb) ^ X)) = p4;
        };

        auto MFMA2 = [&](bf16x8 kf0, bf16x8 kf1) {
            f32x4 acc = {0.f, 0.f, 0.f, 0.f};
            acc = __builtin_amdgcn_mfma_f32_16x16x32_bf16(kf0, qF0, acc, 0, 0, 0);
            acc = __builtin_amdgcn_mfma_f32_16x16x32_bf16(kf1, qF1, acc, 0, 0, 0);
            return acc;
        };

        f32x4 aA, aB;
        #define CITER(B, NT, W, PF, AC, AP, NP) \
            WAITV(W); SBAR(); \
            { bf16x8 kf0 = *(const bf16x8*)(kst + (B)*2048 + lr*128 + ((((akg))  ^(lr&7)) << 4)); \
              bf16x8 kf1 = *(const bf16x8*)(kst + (B)*2048 + lr*128 + ((((akg)+4)^(lr&7)) << 4)); \
              if ((NP) >= 0) CVALU(AP, start + (NP)); \
              WAITLGKM(); SBAR(); \
              if (PF) KSTAGE((B), start + (NT) + 2); \
              AC = MFMA2(kf0, kf1); } \
            SBAR()
        CITER(0, 0, 2, 1, aA, aB, -1);
        CITER(1, 1, 2, 1, aB, aA,  0);
        CITER(0, 2, 2, 1, aA, aB,  1);
        CITER(1, 3, 2, 1, aB, aA,  2);
        CITER(0, 4, 2, 1, aA, aB,  3);
        CITER(1, 5, 2, 0, aB, aA,  4);
        CITER(0, 6, 0, 0, aA, aB,  5);
        if (real7) CVALU(aA, start + 6);         // slot-6 finish only for 7-tile waves
        #undef CITER

        // Prologue hoist for F: stage first two V tiles (F waves w<8 only)
        if (w < 8) {
            WAITLGKM(); SBAR();
            const short* vgbase = vt + ((size_t)bh * DD + (w & 3) * 16) * TT;
            const int S0 = (w >> 2) * 8;
            gload16(vgbase + (size_t)srl * TT + S0 * 64 + sqg * 8,           kst);
            gload16(vgbase + (size_t)(8 + srl) * TT + S0 * 64 + sqg * 8,     kst + 1024);
            gload16(vgbase + (size_t)srl * TT + (S0 + 1) * 64 + sqg * 8,     kst + 2048);
            gload16(vgbase + (size_t)(8 + srl) * TT + (S0 + 1) * 64 + sqg * 8, kst + 3072);
        }

        sum  += __shfl_xor(sum, 16);  sum  += __shfl_xor(sum, 32);
        suff += __shfl_xor(suff, 16); suff += __shfl_xor(suff, 32);
        msum += __shfl_xor(msum, 16); msum += __shfl_xor(msum, 32);
        if (lane < 16) {
            psum_lds[lr][w] = f2bf(sum);
            psuf_lds[lr][w] = f2bf(suff);
            pmid_lds[lr][w] = f2bf(msum);
        }
    }
    __syncthreads();

    // ---- D1: finalize per-row sums ----
    if (t < QBLK) {
        float s = 0.f, sf = 0.f, sm = 0.f;
        #pragma unroll
        for (int i = 0; i < NW; ++i) {
            s  += bf2f(psum_lds[t][i]);
            sf += bf2f(psuf_lds[t][i]);
            sm += bf2f(pmid_lds[t][i]);
        }
        inv_lds[t] = 1.0f / s;
        w_lds[t * NV]      = s - sf - sm;   // prefix weight (v=0)
        w_lds[t * NV + 32] = sf;            // suffix weight (v=32)
    }
    __syncthreads();

    // ---- Phase F (waves 0..7): dt = w&3, sh = w>>2; attn stores interleaved ----
    f32x4 facc = {0.f, 0.f, 0.f, 0.f};
    if (w < 8) {
        const int dt = w & 3;
        const int sh = w >> 2;
        const int S0 = sh * 8;
        const int lc = lane & 15;
        const char* pb = pbuf + lc * 2048;
        const int X = (lc & 7) << 4;
        char* vst = kst;
        const short* vgbase = vt + ((size_t)bh * DD + dt * 16) * TT;
        float* ab = attn_g + ((size_t)bh * TT + q0) * TT;
        f32x4 acc0 = {0.f, 0.f, 0.f, 0.f};
        f32x4 acc1 = {0.f, 0.f, 0.f, 0.f};

        auto VSTAGE = [&](int B, int S) {
            gload16(vgbase + (size_t)srl * TT + S * 64 + sqg * 8,       vst + B * 2048);
            gload16(vgbase + (size_t)(8 + srl) * TT + S * 64 + sqg * 8, vst + B * 2048 + 1024);
        };

        auto ASTORE = [&](int ST) {
            const int r_ = w * 2 + (ST >> 2);
            const int i_ = ST & 3;
            const float inv_ = inv_lds[r_];
            const int Xr = (r_ & 7) << 4;
            bf16x4 p4 = *(const bf16x4*)(pbuf + r_ * 2048 + ((8 * lane + 512 * i_) ^ Xr));
            f32x4 o;
            o[0] = bf2f(p4[0]) * inv_; o[1] = bf2f(p4[1]) * inv_;
            o[2] = bf2f(p4[2]) * inv_; o[3] = bf2f(p4[3]) * inv_;
            __builtin_nontemporal_store(o, (f32x4*)(ab + (size_t)r_ * TT + lane * 4 + 256 * i_));
        };

        #define FITER(B, S, W, PF, AC, ST) \
            WAITV(W); SBAR(); \
            { ASTORE(ST); \
              bf16x8 vf0 = *(const bf16x8*)(vst + (B)*2048 + lc*128 + ((((akg))  ^(lc&7)) << 4)); \
              bf16x8 vf1 = *(const bf16x8*)(vst + (B)*2048 + lc*128 + ((((akg)+4)^(lc&7)) << 4)); \
              bf16x8 a0 = *(const bf16x8*)(pb + (((2*(S))*64     + akg*16) ^ X)); \
              bf16x8 a1 = *(const bf16x8*)(pb + (((2*(S)+1)*64   + akg*16) ^ X)); \
              WAITLGKM(); SBAR(); \
              if (PF) VSTAGE((B), (S) + 2); \
              AC = __builtin_amdgcn_mfma_f32_16x16x32_bf16(a0, vf0, AC, 0, 0, 0); \
              AC = __builtin_amdgcn_mfma_f32_16x16x32_bf16(a1, vf1, AC, 0, 0, 0); } \
            SBAR()
        FITER(0, S0 + 0, 2, 1, acc0, 0);  FITER(1, S0 + 1, 2, 1, acc1, 1);
        FITER(0, S0 + 2, 2, 1, acc0, 2);  FITER(1, S0 + 3, 2, 1, acc1, 3);
        FITER(0, S0 + 4, 2, 1, acc0, 4);  FITER(1, S0 + 5, 2, 1, acc1, 5);
        FITER(0, S0 + 6, 2, 0, acc0, 6);  FITER(1, S0 + 7, 0, 0, acc1, 7);
        #undef FITER

        facc[0] = acc0[0] + acc1[0]; facc[1] = acc0[1] + acc1[1];
        facc[2] = acc0[2] + acc1[2]; facc[3] = acc0[3] + acc1[3];

        if (sh == 1) {
            const int lc2 = lane & 15;
            #pragma unroll
            for (int j = 0; j < 4; ++j)
                pair_lds[dt][akg * 4 + j][lc2] = f2bf(facc[j]);
        }
    }
    __syncthreads();

    if (w < 4) {   // sh == 0 waves finish out
        const int dt = w & 3;
        const int lc = lane & 15;
        const int dcol = dt * 16 + lc;
        const int rb = akg * 4;
        float o0 = facc[0] + bf2f(pair_lds[dt][rb + 0][lc]);
        float o1 = facc[1] + bf2f(pair_lds[dt][rb + 1][lc]);
        float o2 = facc[2] + bf2f(pair_lds[dt][rb + 2][lc]);
        float o3 = facc[3] + bf2f(pair_lds[dt][rb + 3][lc]);
        #pragma unroll 8
        for (int v = 0; v < NV; ++v) {
            float ev = ev_g[v * DD + dcol];
            o0 += w_lds[(rb + 0) * NV + v] * ev;
            o1 += w_lds[(rb + 1) * NV + v] * ev;
            o2 += w_lds[(rb + 2) * NV + v] * ev;
            o3 += w_lds[(rb + 3) * NV + v] * ev;
        }
        float* op = out_g + ((size_t)bh * TT + q0 + rb) * DD + dcol;
        op[0 * DD] = o0 * inv_lds[rb + 0];
        op[1 * DD] = o1 * inv_lds[rb + 1];
        op[2 * DD] = o2 * inv_lds[rb + 2];
        op[3 * DD] = o3 * inv_lds[rb + 3];
    }
}

extern "C" void kernel_launch(void* const* d_in, const int* in_sizes, int n_in,
                              void* d_out, int out_size, void* d_ws, size_t ws_size,
                              hipStream_t stream) {
    const float* q  = (const float*)d_in[0];
    const float* k  = (const float*)d_in[1];
    const float* v  = (const float*)d_in[2];
    const float* ek = (const float*)d_in[3];
    const float* ev = (const float*)d_in[4];
    float* out  = (float*)d_out;
    float* attn = out + (size_t)BH * TT * DD;

    short* kbuf = (short*)d_ws;
    short* vtb  = kbuf + (size_t)BH * TT * DD;

    prep_kernel<<<dim3(1024), dim3(256), 0, stream>>>(k, v, kbuf, vtb);
    relattn_kernel<<<dim3(4096), dim3(640), 0, stream>>>(q, kbuf, vtb, ek, ev, out, attn);
}

// Round 24
// 135.079 us; speedup vs baseline: 1.0743x; 1.0743x over previous
//
#include <hip/hip_runtime.h>
#include <hip/hip_bf16.h>

#define TT 1024
#define DD 64
#define MAXREL 16
#define NV 33
#define QBLK 16
#define SCALE 0.125f
#define BH 64

typedef short bf16x8 __attribute__((ext_vector_type(8)));
typedef short bf16x4 __attribute__((ext_vector_type(4)));
typedef float f32x4 __attribute__((ext_vector_type(4)));

#define SBAR() __builtin_amdgcn_sched_barrier(0)
#define WAITV(N)   __builtin_amdgcn_s_waitcnt(0x0F70 | (N))   // lgkm=15, exp=7, vm=N
#define WAITLGKM() __builtin_amdgcn_s_waitcnt(0xC07F)          // vm=63, exp=7, lgkm=0

static __device__ inline void gload16(const void* g, void* l) {
    __builtin_amdgcn_global_load_lds(
        (const __attribute__((address_space(1))) void*)g,
        (__attribute__((address_space(3))) void*)l, 16, 0, 0);
}

static __device__ inline short f2bf(float f) {
    __hip_bfloat16 h = __float2bfloat16(f);
    return *(short*)&h;
}
static __device__ inline float bf2f(short s) {
    union { unsigned u; float f; } x;
    x.u = ((unsigned)(unsigned short)s) << 16;
    return x.f;
}
static __device__ inline bf16x8 pack8(float4 a, float4 b) {
    bf16x8 r;
    r[0]=f2bf(a.x); r[1]=f2bf(a.y); r[2]=f2bf(a.z); r[3]=f2bf(a.w);
    r[4]=f2bf(b.x); r[5]=f2bf(b.y); r[6]=f2bf(b.z); r[7]=f2bf(b.w);
    return r;
}

// ---- pre-kernel 1: K f32 -> bf16 ----
__global__ __launch_bounds__(256)
void convk_kernel(const float* __restrict__ src, short* __restrict__ dst) {
    size_t i = (size_t)blockIdx.x * 256 + threadIdx.x;
    const float4* s = (const float4*)(src + i * 8);
    *(bf16x8*)(dst + i * 8) = pack8(s[0], s[1]);
}

// ---- pre-kernel 2: V [bh][s][d] f32 -> vt [bh][d][s] bf16 ----
__global__ __launch_bounds__(256)
void transv_kernel(const float* __restrict__ v, short* __restrict__ vt) {
    int bh = blockIdx.x >> 4;
    int st = blockIdx.x & 15;
    int wave = threadIdx.x >> 6, lane = threadIdx.x & 63;
    int s0 = st * 64 + wave * 16;
    const float* vp = v + ((size_t)bh * TT + s0) * DD + lane;
    bf16x8 lo, hi;
    #pragma unroll
    for (int e = 0; e < 8; ++e) lo[e] = f2bf(vp[(size_t)e * DD]);
    #pragma unroll
    for (int e = 0; e < 8; ++e) hi[e] = f2bf(vp[(size_t)(e + 8) * DD]);
    short* dp = vt + ((size_t)bh * DD + lane) * TT + s0;
    *(bf16x8*)dp = lo;
    *(bf16x8*)(dp + 8) = hi;
}

__global__ __launch_bounds__(512)
void relattn_kernel(const float* __restrict__ q_g,
                    const short* __restrict__ kb,
                    const short* __restrict__ vt,
                    const float* __restrict__ ek_g,
                    const float* __restrict__ ev_g,
                    float* __restrict__ out_g,
                    float* __restrict__ attn_g) {
    __shared__ __align__(16) char pbuf[QBLK * 2048];     // 32768 B bf16 P, swizzled
    __shared__ __align__(16) char kstage[8 * 4096];      // per-wave K/V stage (2x2KB x 8 waves)
    __shared__ float pair_lds[4][16][16];                // 4096 B: F s-half reduction
    __shared__ float qe_lds[QBLK * NV];                  // eqe = exp(qe/8)
    __shared__ float w_lds[QBLK * NV];                   // unnormalized w
    __shared__ float psum_lds[QBLK][8];
    __shared__ float psuf_lds[QBLK][8];
    __shared__ float pmid_lds[QBLK][8];
    __shared__ float inv_lds[QBLK];

    const int t    = threadIdx.x;
    const int bid  = blockIdx.x;
    const int wg   = ((bid & 7) << 9) | (bid >> 3);      // XCD swizzle
    const int bh   = wg >> 6;
    const int q0   = (wg & 63) * QBLK;
    const int w    = t >> 6;                             // wave 0..7
    const int lane = t & 63;
    const int lr   = lane & 15;
    const int akg  = lane >> 4;
    const int srl  = lane >> 3;                          // staging row-local 0..7
    const int sqg  = (lane & 7) ^ srl;                   // pre-swizzled quad index

    const short* kgbase = kb + (size_t)bh * TT * DD;
    char* kst = kstage + w * 4096;                       // wave-private 2x2KB

    auto KSTAGE = [&](int B, int NT) {
        const int s0 = w * 128 + NT * 16;
        gload16(kgbase + (size_t)(s0 + srl) * 64 + sqg * 8,     kst + B * 2048);
        gload16(kgbase + (size_t)(s0 + 8 + srl) * 64 + sqg * 8, kst + B * 2048 + 1024);
    };

    // Q fragment (B operand of swapped MFMA): Q[q0+lr][...]
    bf16x8 qF0, qF1;
    {
        const float* qp = q_g + ((size_t)bh * TT + q0 + lr) * DD + akg * 8;
        float4 a = *(const float4*)qp,        b = *(const float4*)(qp + 4);
        float4 c = *(const float4*)(qp + 32), d = *(const float4*)(qp + 36);
        qF0 = pack8(a, b); qF1 = pack8(c, d);
    }

    // Prologue hoist: stage first two K tiles; Phase A + barrier cover latency
    KSTAGE(0, 0); KSTAGE(1, 1);

    // ---- Phase A: zero w; eqe = exp(qe/8) via MFMA (waves 0..2) ----
    for (int i = t; i < QBLK * NV; i += 512) w_lds[i] = 0.f;
    if (w < 3) {
        int v = w * 16 + lr; if (v > 32) v = 32;
        const float* ep = ek_g + v * DD + akg * 8;
        float4 a = *(const float4*)ep,        b = *(const float4*)(ep + 4);
        float4 c = *(const float4*)(ep + 32), d = *(const float4*)(ep + 36);
        bf16x8 eF0 = pack8(a, b), eF1 = pack8(c, d);
        f32x4 qacc = {0.f, 0.f, 0.f, 0.f};
        qacc = __builtin_amdgcn_mfma_f32_16x16x32_bf16(eF0, qF0, qacc, 0, 0, 0);
        qacc = __builtin_amdgcn_mfma_f32_16x16x32_bf16(eF1, qF1, qacc, 0, 0, 0);
        #pragma unroll
        for (int j = 0; j < 4; ++j) {
            int vv = w * 16 + akg * 4 + j;
            if (vv < NV) qe_lds[lr * NV + vv] = __expf(qacc[j] * SCALE);
        }
    }
    __syncthreads();

    // ---- Phase C: wave-private 128-wide s-slice, 8 iters ----
    {
        const int tq = q0 + lr;
        const int X  = (lr & 7) << 4;
        const float eqe_lo = qe_lds[lr * NV];
        const float eqe_hi = qe_lds[lr * NV + 32];
        float sum = 0.f, suff = 0.f, msum = 0.f;

        auto CVALU = [&](f32x4 acc, int nt) {
            const int sb = w * 128 + nt * 16 + akg * 4;
            float ex0 = __expf(acc[0] * SCALE), ex1 = __expf(acc[1] * SCALE);
            float ex2 = __expf(acc[2] * SCALE), ex3 = __expf(acc[3] * SCALE);
            float e0, e1, e2, e3;
            if (sb >= tq + MAXREL) {               // fully suffix
                e0 = ex0 * eqe_hi; e1 = ex1 * eqe_hi;
                e2 = ex2 * eqe_hi; e3 = ex3 * eqe_hi;
                float csum = (e0 + e1) + (e2 + e3);
                sum += csum; suff += csum;
            } else if (sb + 3 <= tq - MAXREL) {    // fully prefix
                e0 = ex0 * eqe_lo; e1 = ex1 * eqe_lo;
                e2 = ex2 * eqe_lo; e3 = ex3 * eqe_lo;
                sum += (e0 + e1) + (e2 + e3);
            } else {                               // diagonal band (rare)
                float ee[4]; float exs[4] = {ex0, ex1, ex2, ex3};
                #pragma unroll
                for (int j = 0; j < 4; ++j) {
                    int dr = sb + j - tq;
                    int dc = dr < -MAXREL ? -MAXREL : (dr > MAXREL ? MAXREL : dr);
                    float v = exs[j] * qe_lds[lr * NV + dc + MAXREL];
                    ee[j] = v;
                    sum += v;
                    if (dr >= MAXREL) suff += v;
                    if (dr > -MAXREL && dr < MAXREL) {
                        w_lds[lr * NV + dr + MAXREL] = v;
                        msum += v;
                    }
                }
                e0 = ee[0]; e1 = ee[1]; e2 = ee[2]; e3 = ee[3];
            }
            bf16x4 p4;
            p4[0] = f2bf(e0); p4[1] = f2bf(e1);
            p4[2] = f2bf(e2); p4[3] = f2bf(e3);
            *(bf16x4*)(pbuf + lr * 2048 + ((2 * sb) ^ X)) = p4;
        };

        auto MFMA2 = [&](bf16x8 kf0, bf16x8 kf1) {
            f32x4 acc = {0.f, 0.f, 0.f, 0.f};
            acc = __builtin_amdgcn_mfma_f32_16x16x32_bf16(kf0, qF0, acc, 0, 0, 0);
            acc = __builtin_amdgcn_mfma_f32_16x16x32_bf16(kf1, qF1, acc, 0, 0, 0);
            return acc;
        };

        f32x4 aA, aB;
        #define CITER(B, NT, W, PF, AC, AP, NP) \
            WAITV(W); SBAR(); \
            { bf16x8 kf0 = *(const bf16x8*)(kst + (B)*2048 + lr*128 + ((((akg))  ^(lr&7)) << 4)); \
              bf16x8 kf1 = *(const bf16x8*)(kst + (B)*2048 + lr*128 + ((((akg)+4)^(lr&7)) << 4)); \
              if ((NP) >= 0) CVALU(AP, NP); \
              WAITLGKM(); SBAR(); \
              if (PF) KSTAGE((B), (NT) + 2); \
              AC = MFMA2(kf0, kf1); } \
            SBAR()
        CITER(0, 0, 2, 1, aA, aB, -1);
        CITER(1, 1, 2, 1, aB, aA,  0);
        CITER(0, 2, 2, 1, aA, aB,  1);
        CITER(1, 3, 2, 1, aB, aA,  2);
        CITER(0, 4, 2, 1, aA, aB,  3);
        CITER(1, 5, 2, 1, aB, aA,  4);
        CITER(0, 6, 2, 0, aA, aB,  5);
        CITER(1, 7, 0, 0, aB, aA,  6);
        CVALU(aB, 7);
        #undef CITER

        // Prologue hoist for F: stage first two V tiles of this wave's s-half
        {
            WAITLGKM(); SBAR();
            const short* vgbase = vt + ((size_t)bh * DD + (w & 3) * 16) * TT;
            const int S0 = (w >> 2) * 8;
            gload16(vgbase + (size_t)srl * TT + S0 * 64 + sqg * 8,           kst);
            gload16(vgbase + (size_t)(8 + srl) * TT + S0 * 64 + sqg * 8,     kst + 1024);
            gload16(vgbase + (size_t)srl * TT + (S0 + 1) * 64 + sqg * 8,     kst + 2048);
            gload16(vgbase + (size_t)(8 + srl) * TT + (S0 + 1) * 64 + sqg * 8, kst + 3072);
        }

        sum  += __shfl_xor(sum, 16);  sum  += __shfl_xor(sum, 32);
        suff += __shfl_xor(suff, 16); suff += __shfl_xor(suff, 32);
        msum += __shfl_xor(msum, 16); msum += __shfl_xor(msum, 32);
        if (lane < 16) {
            psum_lds[lr][w] = sum;
            psuf_lds[lr][w] = suff;
            pmid_lds[lr][w] = msum;
        }
    }
    __syncthreads();

    // ---- D1: finalize per-row sums ----
    if (t < QBLK) {
        float s = 0.f, sf = 0.f, sm = 0.f;
        #pragma unroll
        for (int i = 0; i < 8; ++i) {
            s  += psum_lds[t][i];
            sf += psuf_lds[t][i];
            sm += pmid_lds[t][i];
        }
        inv_lds[t] = 1.0f / s;
        w_lds[t * NV]      = s - sf - sm;   // prefix weight (v=0)
        w_lds[t * NV + 32] = sf;            // suffix weight (v=32)
    }
    __syncthreads();

    // ---- Phase F: wave (dt = w&3, s-half = w>>2); dual accumulators ----
    {
        const int dt = w & 3;
        const int sh = w >> 2;
        const int S0 = sh * 8;
        const int lc = lane & 15;
        const int dcol = dt * 16 + lc;
        const char* pb = pbuf + lc * 2048;
        const int X = (lc & 7) << 4;
        char* vst = kst;
        const short* vgbase = vt + ((size_t)bh * DD + dt * 16) * TT;
        f32x4 acc0 = {0.f, 0.f, 0.f, 0.f};
        f32x4 acc1 = {0.f, 0.f, 0.f, 0.f};

        auto VSTAGE = [&](int B, int S) {
            gload16(vgbase + (size_t)srl * TT + S * 64 + sqg * 8,       vst + B * 2048);
            gload16(vgbase + (size_t)(8 + srl) * TT + S * 64 + sqg * 8, vst + B * 2048 + 1024);
        };

        #define FITER(B, S, W, PF, AC) \
            WAITV(W); SBAR(); \
            { bf16x8 vf0 = *(const bf16x8*)(vst + (B)*2048 + lc*128 + ((((akg))  ^(lc&7)) << 4)); \
              bf16x8 vf1 = *(const bf16x8*)(vst + (B)*2048 + lc*128 + ((((akg)+4)^(lc&7)) << 4)); \
              bf16x8 a0 = *(const bf16x8*)(pb + (((2*(S))*64     + akg*16) ^ X)); \
              bf16x8 a1 = *(const bf16x8*)(pb + (((2*(S)+1)*64   + akg*16) ^ X)); \
              WAITLGKM(); SBAR(); \
              if (PF) VSTAGE((B), (S) + 2); \
              AC = __builtin_amdgcn_mfma_f32_16x16x32_bf16(a0, vf0, AC, 0, 0, 0); \
              AC = __builtin_amdgcn_mfma_f32_16x16x32_bf16(a1, vf1, AC, 0, 0, 0); } \
            SBAR()
        FITER(0, S0 + 0, 2, 1, acc0);  FITER(1, S0 + 1, 2, 1, acc1);
        FITER(0, S0 + 2, 2, 1, acc0);  FITER(1, S0 + 3, 2, 1, acc1);
        FITER(0, S0 + 4, 2, 1, acc0);  FITER(1, S0 + 5, 2, 1, acc1);
        FITER(0, S0 + 6, 2, 0, acc0);  FITER(1, S0 + 7, 0, 0, acc1);
        #undef FITER

        f32x4 acc;
        acc[0] = acc0[0] + acc1[0]; acc[1] = acc0[1] + acc1[1];
        acc[2] = acc0[2] + acc1[2]; acc[3] = acc0[3] + acc1[3];

        // s-half reduction: upper waves publish partials
        if (sh == 1) {
            #pragma unroll
            for (int j = 0; j < 4; ++j)
                pair_lds[dt][akg * 4 + j][lc] = acc[j];
        }
        __syncthreads();

        if (sh == 0) {
            const int rb = akg * 4;
            float o0 = acc[0] + pair_lds[dt][rb + 0][lc];
            float o1 = acc[1] + pair_lds[dt][rb + 1][lc];
            float o2 = acc[2] + pair_lds[dt][rb + 2][lc];
            float o3 = acc[3] + pair_lds[dt][rb + 3][lc];
            #pragma unroll 8
            for (int v = 0; v < NV; ++v) {
                float ev = ev_g[v * DD + dcol];
                o0 += w_lds[(rb + 0) * NV + v] * ev;
                o1 += w_lds[(rb + 1) * NV + v] * ev;
                o2 += w_lds[(rb + 2) * NV + v] * ev;
                o3 += w_lds[(rb + 3) * NV + v] * ev;
            }
            float* op = out_g + ((size_t)bh * TT + q0 + rb) * DD + dcol;
            op[0 * DD] = o0 * inv_lds[rb + 0];
            op[1 * DD] = o1 * inv_lds[rb + 1];
            op[2 * DD] = o2 * inv_lds[rb + 2];
            op[3 * DD] = o3 * inv_lds[rb + 3];
        }
    }

    // ---- D2: normalized attn write (plain stores, coalesced; 2 rows/wave) ----
    {
        float* ab = attn_g + ((size_t)bh * TT + q0) * TT;
        #pragma unroll
        for (int j = 0; j < 2; ++j) {
            const int r = w * 2 + j;
            const float inv = inv_lds[r];
            const int X = (r & 7) << 4;
            #pragma unroll
            for (int i = 0; i < 4; ++i) {
                bf16x4 p4 = *(const bf16x4*)(pbuf + r * 2048 + ((8 * lane + 512 * i) ^ X));
                f32x4 o;
                o[0] = bf2f(p4[0]) * inv; o[1] = bf2f(p4[1]) * inv;
                o[2] = bf2f(p4[2]) * inv; o[3] = bf2f(p4[3]) * inv;
                *(f32x4*)(ab + (size_t)r * TT + lane * 4 + 256 * i) = o;
            }
        }
    }
}

extern "C" void kernel_launch(void* const* d_in, const int* in_sizes, int n_in,
                              void* d_out, int out_size, void* d_ws, size_t ws_size,
                              hipStream_t stream) {
    const float* q  = (const float*)d_in[0];
    const float* k  = (const float*)d_in[1];
    const float* v  = (const float*)d_in[2];
    const float* ek = (const float*)d_in[3];
    const float* ev = (const float*)d_in[4];
    float* out  = (float*)d_out;
    float* attn = out + (size_t)BH * TT * DD;

    short* kbuf = (short*)d_ws;
    short* vtb  = kbuf + (size_t)BH * TT * DD;

    convk_kernel<<<dim3(2048), dim3(256), 0, stream>>>(k, kbuf);
    transv_kernel<<<dim3(1024), dim3(256), 0, stream>>>(v, vtb);
    relattn_kernel<<<dim3(4096), dim3(512), 0, stream>>>(q, kbuf, vtb, ek, ev, out, attn);
}

// Round 25
// 118.722 us; speedup vs baseline: 1.2223x; 1.1378x over previous
//
#include <hip/hip_runtime.h>
#include <hip/hip_bf16.h>

#define TT 1024
#define DD 64
#define MAXREL 16
#define NV 33
#define QBLK 16
#define SCALE 0.125f
#define BH 64

typedef short bf16x8 __attribute__((ext_vector_type(8)));
typedef short bf16x4 __attribute__((ext_vector_type(4)));
typedef float f32x4 __attribute__((ext_vector_type(4)));

#define SBAR() __builtin_amdgcn_sched_barrier(0)
#define WAITV(N)   __builtin_amdgcn_s_waitcnt(0x0F70 | (N))   // lgkm=15, exp=7, vm=N
#define WAITLGKM() __builtin_amdgcn_s_waitcnt(0xC07F)          // vm=63, exp=7, lgkm=0

static __device__ inline void gload16(const void* g, void* l) {
    __builtin_amdgcn_global_load_lds(
        (const __attribute__((address_space(1))) void*)g,
        (__attribute__((address_space(3))) void*)l, 16, 0, 0);
}

static __device__ inline short f2bf(float f) {
    __hip_bfloat16 h = __float2bfloat16(f);
    return *(short*)&h;
}
static __device__ inline float bf2f(short s) {
    union { unsigned u; float f; } x;
    x.u = ((unsigned)(unsigned short)s) << 16;
    return x.f;
}
static __device__ inline bf16x8 pack8(float4 a, float4 b) {
    bf16x8 r;
    r[0]=f2bf(a.x); r[1]=f2bf(a.y); r[2]=f2bf(a.z); r[3]=f2bf(a.w);
    r[4]=f2bf(b.x); r[5]=f2bf(b.y); r[6]=f2bf(b.z); r[7]=f2bf(b.w);
    return r;
}

// ---- pre-kernel 1: K f32 -> bf16 ----
__global__ __launch_bounds__(256)
void convk_kernel(const float* __restrict__ src, short* __restrict__ dst) {
    size_t i = (size_t)blockIdx.x * 256 + threadIdx.x;
    const float4* s = (const float4*)(src + i * 8);
    *(bf16x8*)(dst + i * 8) = pack8(s[0], s[1]);
}

// ---- pre-kernel 2: V [bh][s][d] f32 -> vt [bh][d][s] bf16 ----
__global__ __launch_bounds__(256)
void transv_kernel(const float* __restrict__ v, short* __restrict__ vt) {
    int bh = blockIdx.x >> 4;
    int st = blockIdx.x & 15;
    int wave = threadIdx.x >> 6, lane = threadIdx.x & 63;
    int s0 = st * 64 + wave * 16;
    const float* vp = v + ((size_t)bh * TT + s0) * DD + lane;
    bf16x8 lo, hi;
    #pragma unroll
    for (int e = 0; e < 8; ++e) lo[e] = f2bf(vp[(size_t)e * DD]);
    #pragma unroll
    for (int e = 0; e < 8; ++e) hi[e] = f2bf(vp[(size_t)(e + 8) * DD]);
    short* dp = vt + ((size_t)bh * DD + lane) * TT + s0;
    *(bf16x8*)dp = lo;
    *(bf16x8*)(dp + 8) = hi;
}

__global__ __launch_bounds__(512)
void relattn_kernel(const float* __restrict__ q_g,
                    const short* __restrict__ kb,
                    const short* __restrict__ vt,
                    const float* __restrict__ ek_g,
                    const float* __restrict__ ev_g,
                    float* __restrict__ out_g,
                    float* __restrict__ attn_g) {
    __shared__ __align__(16) char pbuf[QBLK * 2048];     // 32768 B bf16 P, swizzled
    __shared__ __align__(16) char kstage[8 * 4096];      // per-wave K/V stage (2x2KB x 8 waves)
    __shared__ float pair_lds[4][16][16];                // 4096 B: F s-half reduction
    __shared__ float qe_lds[QBLK * NV];                  // eqe = exp(qe/8)
    __shared__ float w_lds[QBLK * NV];                   // unnormalized w
    __shared__ float psum_lds[QBLK][8];
    __shared__ float psuf_lds[QBLK][8];
    __shared__ float pmid_lds[QBLK][8];
    __shared__ float inv_lds[QBLK];

    const int t    = threadIdx.x;
    const int bid  = blockIdx.x;
    const int wg   = ((bid & 7) << 9) | (bid >> 3);      // XCD swizzle
    const int bh   = wg >> 6;
    const int q0   = (wg & 63) * QBLK;
    const int w    = t >> 6;                             // wave 0..7
    const int lane = t & 63;
    const int lr   = lane & 15;
    const int akg  = lane >> 4;
    const int srl  = lane >> 3;                          // staging row-local 0..7
    const int sqg  = (lane & 7) ^ srl;                   // pre-swizzled quad index

    const short* kgbase = kb + (size_t)bh * TT * DD;
    char* kst = kstage + w * 4096;                       // wave-private 2x2KB

    auto KSTAGE = [&](int B, int NT) {
        const int s0 = w * 128 + NT * 16;
        gload16(kgbase + (size_t)(s0 + srl) * 64 + sqg * 8,     kst + B * 2048);
        gload16(kgbase + (size_t)(s0 + 8 + srl) * 64 + sqg * 8, kst + B * 2048 + 1024);
    };

    // Q fragment (B operand of swapped MFMA): Q[q0+lr][...]
    bf16x8 qF0, qF1;
    {
        const float* qp = q_g + ((size_t)bh * TT + q0 + lr) * DD + akg * 8;
        float4 a = *(const float4*)qp,        b = *(const float4*)(qp + 4);
        float4 c = *(const float4*)(qp + 32), d = *(const float4*)(qp + 36);
        qF0 = pack8(a, b); qF1 = pack8(c, d);
    }

    // Prologue hoist: stage first two K tiles; Phase A + barrier cover latency
    KSTAGE(0, 0); KSTAGE(1, 1);

    // ---- Phase A: zero w; eqe = exp(qe/8) via MFMA (waves 0..2) ----
    for (int i = t; i < QBLK * NV; i += 512) w_lds[i] = 0.f;
    if (w < 3) {
        int v = w * 16 + lr; if (v > 32) v = 32;
        const float* ep = ek_g + v * DD + akg * 8;
        float4 a = *(const float4*)ep,        b = *(const float4*)(ep + 4);
        float4 c = *(const float4*)(ep + 32), d = *(const float4*)(ep + 36);
        bf16x8 eF0 = pack8(a, b), eF1 = pack8(c, d);
        f32x4 qacc = {0.f, 0.f, 0.f, 0.f};
        qacc = __builtin_amdgcn_mfma_f32_16x16x32_bf16(eF0, qF0, qacc, 0, 0, 0);
        qacc = __builtin_amdgcn_mfma_f32_16x16x32_bf16(eF1, qF1, qacc, 0, 0, 0);
        #pragma unroll
        for (int j = 0; j < 4; ++j) {
            int vv = w * 16 + akg * 4 + j;
            if (vv < NV) qe_lds[lr * NV + vv] = __expf(qacc[j] * SCALE);
        }
    }
    __syncthreads();

    // ---- Phase C: wave-private 128-wide s-slice, 8 iters ----
    {
        const int tq = q0 + lr;
        const int X  = (lr & 7) << 4;
        const float eqe_lo = qe_lds[lr * NV];
        const float eqe_hi = qe_lds[lr * NV + 32];
        float sum = 0.f, suff = 0.f, msum = 0.f;

        auto CVALU = [&](f32x4 acc, int nt) {
            const int sb = w * 128 + nt * 16 + akg * 4;
            float ex0 = __expf(acc[0] * SCALE), ex1 = __expf(acc[1] * SCALE);
            float ex2 = __expf(acc[2] * SCALE), ex3 = __expf(acc[3] * SCALE);
            float e0, e1, e2, e3;
            if (sb >= tq + MAXREL) {               // fully suffix
                e0 = ex0 * eqe_hi; e1 = ex1 * eqe_hi;
                e2 = ex2 * eqe_hi; e3 = ex3 * eqe_hi;
                float csum = (e0 + e1) + (e2 + e3);
                sum += csum; suff += csum;
            } else if (sb + 3 <= tq - MAXREL) {    // fully prefix
                e0 = ex0 * eqe_lo; e1 = ex1 * eqe_lo;
                e2 = ex2 * eqe_lo; e3 = ex3 * eqe_lo;
                sum += (e0 + e1) + (e2 + e3);
            } else {                               // diagonal band (rare)
                float ee[4]; float exs[4] = {ex0, ex1, ex2, ex3};
                #pragma unroll
                for (int j = 0; j < 4; ++j) {
                    int dr = sb + j - tq;
                    int dc = dr < -MAXREL ? -MAXREL : (dr > MAXREL ? MAXREL : dr);
                    float v = exs[j] * qe_lds[lr * NV + dc + MAXREL];
                    ee[j] = v;
                    sum += v;
                    if (dr >= MAXREL) suff += v;
                    if (dr > -MAXREL && dr < MAXREL) {
                        w_lds[lr * NV + dr + MAXREL] = v;
                        msum += v;
                    }
                }
                e0 = ee[0]; e1 = ee[1]; e2 = ee[2]; e3 = ee[3];
            }
            bf16x4 p4;
            p4[0] = f2bf(e0); p4[1] = f2bf(e1);
            p4[2] = f2bf(e2); p4[3] = f2bf(e3);
            *(bf16x4*)(pbuf + lr * 2048 + ((2 * sb) ^ X)) = p4;
        };

        auto MFMA2 = [&](bf16x8 kf0, bf16x8 kf1) {
            f32x4 acc = {0.f, 0.f, 0.f, 0.f};
            acc = __builtin_amdgcn_mfma_f32_16x16x32_bf16(kf0, qF0, acc, 0, 0, 0);
            acc = __builtin_amdgcn_mfma_f32_16x16x32_bf16(kf1, qF1, acc, 0, 0, 0);
            return acc;
        };

        f32x4 aA, aB;
        #define CITER(B, NT, W, PF, AC, AP, NP) \
            WAITV(W); SBAR(); \
            { bf16x8 kf0 = *(const bf16x8*)(kst + (B)*2048 + lr*128 + ((((akg))  ^(lr&7)) << 4)); \
              bf16x8 kf1 = *(const bf16x8*)(kst + (B)*2048 + lr*128 + ((((akg)+4)^(lr&7)) << 4)); \
              if ((NP) >= 0) CVALU(AP, NP); \
              WAITLGKM(); SBAR(); \
              if (PF) KSTAGE((B), (NT) + 2); \
              AC = MFMA2(kf0, kf1); } \
            SBAR()
        CITER(0, 0, 2, 1, aA, aB, -1);
        CITER(1, 1, 2, 1, aB, aA,  0);
        CITER(0, 2, 2, 1, aA, aB,  1);
        CITER(1, 3, 2, 1, aB, aA,  2);
        CITER(0, 4, 2, 1, aA, aB,  3);
        CITER(1, 5, 2, 1, aB, aA,  4);
        CITER(0, 6, 2, 0, aA, aB,  5);
        CITER(1, 7, 0, 0, aB, aA,  6);
        CVALU(aB, 7);
        #undef CITER

        // Prologue hoist for F: stage first two V tiles of this wave's s-half
        {
            WAITLGKM(); SBAR();
            const short* vgbase = vt + ((size_t)bh * DD + (w & 3) * 16) * TT;
            const int S0 = (w >> 2) * 8;
            gload16(vgbase + (size_t)srl * TT + S0 * 64 + sqg * 8,           kst);
            gload16(vgbase + (size_t)(8 + srl) * TT + S0 * 64 + sqg * 8,     kst + 1024);
            gload16(vgbase + (size_t)srl * TT + (S0 + 1) * 64 + sqg * 8,     kst + 2048);
            gload16(vgbase + (size_t)(8 + srl) * TT + (S0 + 1) * 64 + sqg * 8, kst + 3072);
        }

        sum  += __shfl_xor(sum, 16);  sum  += __shfl_xor(sum, 32);
        suff += __shfl_xor(suff, 16); suff += __shfl_xor(suff, 32);
        msum += __shfl_xor(msum, 16); msum += __shfl_xor(msum, 32);
        if (lane < 16) {
            psum_lds[lr][w] = sum;
            psuf_lds[lr][w] = suff;
            pmid_lds[lr][w] = msum;
        }
    }
    __syncthreads();

    // ---- D1: finalize per-row sums ----
    if (t < QBLK) {
        float s = 0.f, sf = 0.f, sm = 0.f;
        #pragma unroll
        for (int i = 0; i < 8; ++i) {
            s  += psum_lds[t][i];
            sf += psuf_lds[t][i];
            sm += pmid_lds[t][i];
        }
        inv_lds[t] = 1.0f / s;
        w_lds[t * NV]      = s - sf - sm;   // prefix weight (v=0)
        w_lds[t * NV + 32] = sf;            // suffix weight (v=32)
    }
    __syncthreads();

    // ---- Phase F: wave (dt = w&3, s-half = w>>2); dual accumulators ----
    {
        const int dt = w & 3;
        const int sh = w >> 2;
        const int S0 = sh * 8;
        const int lc = lane & 15;
        const int dcol = dt * 16 + lc;
        const char* pb = pbuf + lc * 2048;
        const int X = (lc & 7) << 4;
        char* vst = kst;
        const short* vgbase = vt + ((size_t)bh * DD + dt * 16) * TT;
        f32x4 acc0 = {0.f, 0.f, 0.f, 0.f};
        f32x4 acc1 = {0.f, 0.f, 0.f, 0.f};

        auto VSTAGE = [&](int B, int S) {
            gload16(vgbase + (size_t)srl * TT + S * 64 + sqg * 8,       vst + B * 2048);
            gload16(vgbase + (size_t)(8 + srl) * TT + S * 64 + sqg * 8, vst + B * 2048 + 1024);
        };

        #define FITER(B, S, W, PF, AC) \
            WAITV(W); SBAR(); \
            { bf16x8 vf0 = *(const bf16x8*)(vst + (B)*2048 + lc*128 + ((((akg))  ^(lc&7)) << 4)); \
              bf16x8 vf1 = *(const bf16x8*)(vst + (B)*2048 + lc*128 + ((((akg)+4)^(lc&7)) << 4)); \
              bf16x8 a0 = *(const bf16x8*)(pb + (((2*(S))*64     + akg*16) ^ X)); \
              bf16x8 a1 = *(const bf16x8*)(pb + (((2*(S)+1)*64   + akg*16) ^ X)); \
              WAITLGKM(); SBAR(); \
              if (PF) VSTAGE((B), (S) + 2); \
              AC = __builtin_amdgcn_mfma_f32_16x16x32_bf16(a0, vf0, AC, 0, 0, 0); \
              AC = __builtin_amdgcn_mfma_f32_16x16x32_bf16(a1, vf1, AC, 0, 0, 0); } \
            SBAR()
        FITER(0, S0 + 0, 2, 1, acc0);  FITER(1, S0 + 1, 2, 1, acc1);
        FITER(0, S0 + 2, 2, 1, acc0);  FITER(1, S0 + 3, 2, 1, acc1);
        FITER(0, S0 + 4, 2, 1, acc0);  FITER(1, S0 + 5, 2, 1, acc1);
        FITER(0, S0 + 6, 2, 0, acc0);  FITER(1, S0 + 7, 0, 0, acc1);
        #undef FITER

        f32x4 acc;
        acc[0] = acc0[0] + acc1[0]; acc[1] = acc0[1] + acc1[1];
        acc[2] = acc0[2] + acc1[2]; acc[3] = acc0[3] + acc1[3];

        // s-half reduction: upper waves publish partials
        if (sh == 1) {
            #pragma unroll
            for (int j = 0; j < 4; ++j)
                pair_lds[dt][akg * 4 + j][lc] = acc[j];
        }
        __syncthreads();

        if (sh == 0) {
            const int rb = akg * 4;
            float o0 = acc[0] + pair_lds[dt][rb + 0][lc];
            float o1 = acc[1] + pair_lds[dt][rb + 1][lc];
            float o2 = acc[2] + pair_lds[dt][rb + 2][lc];
            float o3 = acc[3] + pair_lds[dt][rb + 3][lc];
            #pragma unroll 8
            for (int v = 0; v < NV; ++v) {
                float ev = ev_g[v * DD + dcol];
                o0 += w_lds[(rb + 0) * NV + v] * ev;
                o1 += w_lds[(rb + 1) * NV + v] * ev;
                o2 += w_lds[(rb + 2) * NV + v] * ev;
                o3 += w_lds[(rb + 3) * NV + v] * ev;
            }
            float* op = out_g + ((size_t)bh * TT + q0 + rb) * DD + dcol;
            op[0 * DD] = o0 * inv_lds[rb + 0];
            op[1 * DD] = o1 * inv_lds[rb + 1];
            op[2 * DD] = o2 * inv_lds[rb + 2];
            op[3 * DD] = o3 * inv_lds[rb + 3];
        }
    }

    // ---- D2: normalized attn write (nontemporal, coalesced; 2 rows/wave) ----
    {
        float* ab = attn_g + ((size_t)bh * TT + q0) * TT;
        #pragma unroll
        for (int j = 0; j < 2; ++j) {
            const int r = w * 2 + j;
            const float inv = inv_lds[r];
            const int X = (r & 7) << 4;
            #pragma unroll
            for (int i = 0; i < 4; ++i) {
                bf16x4 p4 = *(const bf16x4*)(pbuf + r * 2048 + ((8 * lane + 512 * i) ^ X));
                f32x4 o;
                o[0] = bf2f(p4[0]) * inv; o[1] = bf2f(p4[1]) * inv;
                o[2] = bf2f(p4[2]) * inv; o[3] = bf2f(p4[3]) * inv;
                __builtin_nontemporal_store(o, (f32x4*)(ab + (size_t)r * TT + lane * 4 + 256 * i));
            }
        }
    }
}

extern "C" void kernel_launch(void* const* d_in, const int* in_sizes, int n_in,
                              void* d_out, int out_size, void* d_ws, size_t ws_size,
                              hipStream_t stream) {
    const float* q  = (const float*)d_in[0];
    const float* k  = (const float*)d_in[1];
    const float* v  = (const float*)d_in[2];
    const float* ek = (const float*)d_in[3];
    const float* ev = (const float*)d_in[4];
    float* out  = (float*)d_out;
    float* attn = out + (size_t)BH * TT * DD;

    short* kbuf = (short*)d_ws;
    short* vtb  = kbuf + (size_t)BH * TT * DD;

    convk_kernel<<<dim3(2048), dim3(256), 0, stream>>>(k, kbuf);
    transv_kernel<<<dim3(1024), dim3(256), 0, stream>>>(v, vtb);
    relattn_kernel<<<dim3(4096), dim3(512), 0, stream>>>(q, kbuf, vtb, ek, ev, out, attn);
}